// Round 1
// baseline (1096.253 us; speedup 1.0000x reference)
//
#include <hip/hip_runtime.h>
#include <cmath>

#define N_NODES 100000
#define N_EDGES 1600000
#define F_IN 512
#define F_HID 128
#define F_OUT 64

// ---------------- CSR build ----------------

__global__ void count_deg_kernel(const int* __restrict__ dst, int* __restrict__ deg, int E) {
    int g = blockIdx.x * blockDim.x + threadIdx.x;
    if (g < E) atomicAdd(&deg[dst[g]], 1);
}

__global__ void dinv_kernel(const int* __restrict__ deg, float* __restrict__ dinv, int n) {
    int g = blockIdx.x * blockDim.x + threadIdx.x;
    if (g < n) dinv[g] = rsqrtf((float)(deg[g] + 1));  // deg includes +1 self loop
}

// single-block exclusive scan of deg -> row_ptr (and cursor copy)
__global__ __launch_bounds__(1024) void scan_kernel(const int* __restrict__ deg,
                                                    int* __restrict__ row_ptr,
                                                    int* __restrict__ cursor, int n) {
    __shared__ int tsum[1024];
    int tid = threadIdx.x;
    int chunk = (n + 1023) / 1024;
    int start = tid * chunk;
    int end = min(start + chunk, n);
    if (start > n) start = n;
    int s = 0;
    for (int i = start; i < end; ++i) s += deg[i];
    tsum[tid] = s;
    __syncthreads();
    // Hillis-Steele inclusive scan over 1024 partials
    for (int d = 1; d < 1024; d <<= 1) {
        int v = (tid >= d) ? tsum[tid - d] : 0;
        __syncthreads();
        tsum[tid] += v;
        __syncthreads();
    }
    int off = tsum[tid] - s;  // exclusive prefix of this chunk
    for (int i = start; i < end; ++i) {
        row_ptr[i] = off;
        cursor[i] = off;
        off += deg[i];
    }
    if (tid == 1023) row_ptr[n] = tsum[1023];
}

__global__ void fill_csr_kernel(const int* __restrict__ src, const int* __restrict__ dst,
                                int* __restrict__ cursor, int* __restrict__ csr_src, int E) {
    int g = blockIdx.x * blockDim.x + threadIdx.x;
    if (g < E) {
        int pos = atomicAdd(&cursor[dst[g]], 1);
        csr_src[pos] = src[g];
    }
}

// ---------------- GEMM (fp32, scaled epilogue: out[r,:] = (A[r,:]@W) * dinv[r]) ----------------
// BM=64, BN=64, BK=16, 256 threads, 4x4 microtile per thread.

#define BM 64
#define BN 64
#define BK 16

__global__ __launch_bounds__(256) void gemm_scale_kernel(
    const float* __restrict__ A, const float* __restrict__ W,
    const float* __restrict__ dinv, float* __restrict__ out,
    int N, int K, int NC) {
    __shared__ float sA[BK][BM + 4];  // transposed A tile: sA[k][m]
    __shared__ float sB[BK][BN + 4];
    int tid = threadIdx.x;
    int row0 = blockIdx.x * BM;
    int col0 = blockIdx.y * BN;
    int trow = tid >> 4;   // 0..15 -> 4 output rows each
    int tcol = tid & 15;   // 0..15 -> 4 output cols each

    // A-tile load mapping: 64 rows x 16 k, float4 per thread
    int arow = tid >> 2;
    int acol = (tid & 3) << 2;
    int grow = row0 + arow;
    if (grow >= N) grow = N - 1;  // clamp (stores are guarded)
    // B-tile load mapping: 16 k x 64 cols, float4 per thread
    int brow = tid >> 4;
    int bcol = (tid & 15) << 2;

    float acc[4][4] = {};
    for (int k0 = 0; k0 < K; k0 += BK) {
        float4 av = *(const float4*)&A[(long)grow * K + k0 + acol];
        float4 bv = *(const float4*)&W[(long)(k0 + brow) * NC + col0 + bcol];
        sA[acol + 0][arow] = av.x;
        sA[acol + 1][arow] = av.y;
        sA[acol + 2][arow] = av.z;
        sA[acol + 3][arow] = av.w;
        *(float4*)&sB[brow][bcol] = bv;
        __syncthreads();
#pragma unroll
        for (int k = 0; k < BK; ++k) {
            float4 a4 = *(const float4*)&sA[k][trow << 2];
            float4 b4 = *(const float4*)&sB[k][tcol << 2];
            float aa[4] = {a4.x, a4.y, a4.z, a4.w};
            float bb[4] = {b4.x, b4.y, b4.z, b4.w};
#pragma unroll
            for (int i = 0; i < 4; ++i)
#pragma unroll
                for (int j = 0; j < 4; ++j)
                    acc[i][j] += aa[i] * bb[j];
        }
        __syncthreads();
    }
#pragma unroll
    for (int i = 0; i < 4; ++i) {
        int r = row0 + (trow << 2) + i;
        if (r < N) {
            float sc = dinv[r];
            float4 o;
            o.x = acc[i][0] * sc;
            o.y = acc[i][1] * sc;
            o.z = acc[i][2] * sc;
            o.w = acc[i][3] * sc;
            *(float4*)&out[(long)r * NC + col0 + (tcol << 2)] = o;
        }
    }
}

// ---------------- aggregation ----------------
// h1[i,t] = relu(dinv[i] * (g1[i,t] + sum_{j in N(i)} g1[j,t]) + b1[t])
__global__ __launch_bounds__(128) void agg1_kernel(
    const float* __restrict__ g1, const int* __restrict__ row_ptr,
    const int* __restrict__ csr_src, const float* __restrict__ dinv,
    const float* __restrict__ b1, float* __restrict__ h1) {
    int i = blockIdx.x;
    int t = threadIdx.x;
    float acc = g1[(long)i * F_HID + t];
    int beg = row_ptr[i], end = row_ptr[i + 1];
    for (int e = beg; e < end; ++e) {
        int j = csr_src[e];
        acc += g1[(long)j * F_HID + t];
    }
    float v = dinv[i] * acc + b1[t];
    h1[(long)i * F_HID + t] = fmaxf(v, 0.0f);
}

// out[i,:] = log_softmax(dinv[i]*(g2[i,:] + sum g2[j,:]) + b2)
__global__ __launch_bounds__(64) void agg2_lsm_kernel(
    const float* __restrict__ g2, const int* __restrict__ row_ptr,
    const int* __restrict__ csr_src, const float* __restrict__ dinv,
    const float* __restrict__ b2, float* __restrict__ out) {
    int i = blockIdx.x;
    int t = threadIdx.x;
    float acc = g2[(long)i * F_OUT + t];
    int beg = row_ptr[i], end = row_ptr[i + 1];
    for (int e = beg; e < end; ++e) {
        int j = csr_src[e];
        acc += g2[(long)j * F_OUT + t];
    }
    float v = dinv[i] * acc + b2[t];
    float m = v;
#pragma unroll
    for (int o = 32; o > 0; o >>= 1) m = fmaxf(m, __shfl_xor(m, o, 64));
    float ex = __expf(v - m);
    float s = ex;
#pragma unroll
    for (int o = 32; o > 0; o >>= 1) s += __shfl_xor(s, o, 64);
    out[(long)i * F_OUT + t] = v - m - __logf(s);
}

// ---------------- launch ----------------

extern "C" void kernel_launch(void* const* d_in, const int* in_sizes, int n_in,
                              void* d_out, int out_size, void* d_ws, size_t ws_size,
                              hipStream_t stream) {
    const float* x  = (const float*)d_in[0];
    const int* eidx = (const int*)d_in[1];   // [2, E]: row 0 = src, row 1 = dst
    const float* W1 = (const float*)d_in[2];
    const float* b1 = (const float*)d_in[3];
    const float* W2 = (const float*)d_in[4];
    const float* b2 = (const float*)d_in[5];
    float* out = (float*)d_out;
    const int* src = eidx;
    const int* dst = eidx + N_EDGES;

    // workspace layout (~110.4 MB total)
    char* base = (char*)d_ws;
    size_t off = 0;
    auto alloc = [&](size_t bytes) -> void* {
        void* p = base + off;
        off += (bytes + 255) & ~(size_t)255;
        return p;
    };
    int* deg      = (int*)alloc((size_t)N_NODES * 4);
    int* row_ptr  = (int*)alloc((size_t)(N_NODES + 1) * 4);
    int* cursor   = (int*)alloc((size_t)N_NODES * 4);
    float* dinv   = (float*)alloc((size_t)N_NODES * 4);
    int* csr_src  = (int*)alloc((size_t)N_EDGES * 4);
    float* g1     = (float*)alloc((size_t)N_NODES * F_HID * 4);
    float* h1     = (float*)alloc((size_t)N_NODES * F_HID * 4);
    float* g2     = g1;  // g1 dead after agg1; reuse for layer-2 scaled GEMM output

    hipMemsetAsync(deg, 0, (size_t)N_NODES * sizeof(int), stream);
    count_deg_kernel<<<(N_EDGES + 255) / 256, 256, 0, stream>>>(dst, deg, N_EDGES);
    dinv_kernel<<<(N_NODES + 255) / 256, 256, 0, stream>>>(deg, dinv, N_NODES);
    scan_kernel<<<1, 1024, 0, stream>>>(deg, row_ptr, cursor, N_NODES);
    fill_csr_kernel<<<(N_EDGES + 255) / 256, 256, 0, stream>>>(src, dst, cursor, csr_src, N_EDGES);

    // layer 1: g1 = (x @ W1) * dinv ; h1 = relu(dinv*(gather-sum g1) + b1)
    gemm_scale_kernel<<<dim3((N_NODES + BM - 1) / BM, F_HID / BN), 256, 0, stream>>>(
        x, W1, dinv, g1, N_NODES, F_IN, F_HID);
    agg1_kernel<<<N_NODES, F_HID, 0, stream>>>(g1, row_ptr, csr_src, dinv, b1, h1);

    // layer 2: g2 = (h1 @ W2) * dinv ; out = log_softmax(dinv*(gather-sum g2) + b2)
    gemm_scale_kernel<<<dim3((N_NODES + BM - 1) / BM, F_OUT / BN), 256, 0, stream>>>(
        h1, W2, dinv, g2, N_NODES, F_HID, F_OUT);
    agg2_lsm_kernel<<<N_NODES, F_OUT, 0, stream>>>(g2, row_ptr, csr_src, dinv, b2, out);
}

// Round 2
// 886.274 us; speedup vs baseline: 1.2369x; 1.2369x over previous
//
#include <hip/hip_runtime.h>
#include <cmath>

#define N_NODES 100000
#define N_EDGES 1600000
#define F_IN 512
#define F_HID 128
#define F_OUT 64

#define SCAN_NB ((N_NODES + 255) / 256)   // 391 blocks

// ---------------- CSR build ----------------

__global__ void count_deg_kernel(const int* __restrict__ dst, int* __restrict__ deg, int E) {
    int g = blockIdx.x * blockDim.x + threadIdx.x;
    if (g < E) atomicAdd(&deg[dst[g]], 1);
}

// two-level scan, stage 1: per-256-block sums
__global__ __launch_bounds__(256) void block_sum_kernel(const int* __restrict__ deg,
                                                        int* __restrict__ bsum, int n) {
    int g = blockIdx.x * 256 + threadIdx.x;
    int v = (g < n) ? deg[g] : 0;
    __shared__ int ws[4];
    int lane = threadIdx.x & 63;
    int w = threadIdx.x >> 6;
#pragma unroll
    for (int o = 32; o > 0; o >>= 1) v += __shfl_down(v, o, 64);
    if (lane == 0) ws[w] = v;
    __syncthreads();
    if (threadIdx.x == 0) bsum[blockIdx.x] = ws[0] + ws[1] + ws[2] + ws[3];
}

// stage 2: exclusive scan of the (<=512) block partials, in place
__global__ __launch_bounds__(512) void scan_partials_kernel(int* __restrict__ bsum, int nb) {
    __shared__ int t[512];
    int tid = threadIdx.x;
    int v = (tid < nb) ? bsum[tid] : 0;
    t[tid] = v;
    __syncthreads();
    for (int d = 1; d < 512; d <<= 1) {
        int u = (tid >= d) ? t[tid - d] : 0;
        __syncthreads();
        t[tid] += u;
        __syncthreads();
    }
    if (tid < nb) bsum[tid] = t[tid] - v;  // exclusive
}

// stage 3: in-block exclusive scan + block offset -> row_ptr/cursor; fused dinv
__global__ __launch_bounds__(256) void scan_final_kernel(const int* __restrict__ deg,
                                                         const int* __restrict__ bsum,
                                                         int* __restrict__ row_ptr,
                                                         int* __restrict__ cursor,
                                                         float* __restrict__ dinv, int n) {
    __shared__ int t[256];
    int g = blockIdx.x * 256 + threadIdx.x;
    int tid = threadIdx.x;
    int v = (g < n) ? deg[g] : 0;
    t[tid] = v;
    __syncthreads();
    for (int d = 1; d < 256; d <<= 1) {
        int u = (tid >= d) ? t[tid - d] : 0;
        __syncthreads();
        t[tid] += u;
        __syncthreads();
    }
    int off = bsum[blockIdx.x] + t[tid] - v;  // global exclusive prefix
    if (g < n) {
        row_ptr[g] = off;
        cursor[g] = off;
        dinv[g] = rsqrtf((float)(v + 1));  // deg + self loop
    }
    if (g == n - 1) row_ptr[n] = off + v;
}

__global__ void fill_csr_kernel(const int* __restrict__ src, const int* __restrict__ dst,
                                int* __restrict__ cursor, int* __restrict__ csr_src, int E) {
    int g = blockIdx.x * blockDim.x + threadIdx.x;
    if (g < E) {
        int pos = atomicAdd(&cursor[dst[g]], 1);
        csr_src[pos] = src[g];
    }
}

// ---------------- GEMM (fp32, scaled epilogue: out[r,:] = (A[r,:]@W) * dinv[r]) ----------------
// BM=64, BN=64, BK=16, 256 threads, 4x4 microtile per thread.

#define BM 64
#define BN 64
#define BK 16

__global__ __launch_bounds__(256) void gemm_scale_kernel(
    const float* __restrict__ A, const float* __restrict__ W,
    const float* __restrict__ dinv, float* __restrict__ out,
    int N, int K, int NC) {
    __shared__ float sA[BK][BM + 4];  // transposed A tile: sA[k][m]
    __shared__ float sB[BK][BN + 4];
    int tid = threadIdx.x;
    int row0 = blockIdx.x * BM;
    int col0 = blockIdx.y * BN;
    int trow = tid >> 4;   // 0..15 -> 4 output rows each
    int tcol = tid & 15;   // 0..15 -> 4 output cols each

    // A-tile load mapping: 64 rows x 16 k, float4 per thread
    int arow = tid >> 2;
    int acol = (tid & 3) << 2;
    int grow = row0 + arow;
    if (grow >= N) grow = N - 1;  // clamp (stores are guarded)
    // B-tile load mapping: 16 k x 64 cols, float4 per thread
    int brow = tid >> 4;
    int bcol = (tid & 15) << 2;

    float acc[4][4] = {};
    for (int k0 = 0; k0 < K; k0 += BK) {
        float4 av = *(const float4*)&A[(long)grow * K + k0 + acol];
        float4 bv = *(const float4*)&W[(long)(k0 + brow) * NC + col0 + bcol];
        sA[acol + 0][arow] = av.x;
        sA[acol + 1][arow] = av.y;
        sA[acol + 2][arow] = av.z;
        sA[acol + 3][arow] = av.w;
        *(float4*)&sB[brow][bcol] = bv;
        __syncthreads();
#pragma unroll
        for (int k = 0; k < BK; ++k) {
            float4 a4 = *(const float4*)&sA[k][trow << 2];
            float4 b4 = *(const float4*)&sB[k][tcol << 2];
            float aa[4] = {a4.x, a4.y, a4.z, a4.w};
            float bb[4] = {b4.x, b4.y, b4.z, b4.w};
#pragma unroll
            for (int i = 0; i < 4; ++i)
#pragma unroll
                for (int j = 0; j < 4; ++j)
                    acc[i][j] += aa[i] * bb[j];
        }
        __syncthreads();
    }
#pragma unroll
    for (int i = 0; i < 4; ++i) {
        int r = row0 + (trow << 2) + i;
        if (r < N) {
            float sc = dinv[r];
            float4 o;
            o.x = acc[i][0] * sc;
            o.y = acc[i][1] * sc;
            o.z = acc[i][2] * sc;
            o.w = acc[i][3] * sc;
            *(float4*)&out[(long)r * NC + col0 + (tcol << 2)] = o;
        }
    }
}

// ---------------- aggregation ----------------
// h1[i,t] = relu(dinv[i] * (g1[i,t] + sum_{j in N(i)} g1[j,t]) + b1[t])
__global__ __launch_bounds__(128) void agg1_kernel(
    const float* __restrict__ g1, const int* __restrict__ row_ptr,
    const int* __restrict__ csr_src, const float* __restrict__ dinv,
    const float* __restrict__ b1, float* __restrict__ h1) {
    int i = blockIdx.x;
    int t = threadIdx.x;
    float acc = g1[(long)i * F_HID + t];
    int beg = row_ptr[i], end = row_ptr[i + 1];
    for (int e = beg; e < end; ++e) {
        int j = csr_src[e];
        acc += g1[(long)j * F_HID + t];
    }
    float v = dinv[i] * acc + b1[t];
    h1[(long)i * F_HID + t] = fmaxf(v, 0.0f);
}

// out[i,:] = log_softmax(dinv[i]*(g2[i,:] + sum g2[j,:]) + b2)
__global__ __launch_bounds__(64) void agg2_lsm_kernel(
    const float* __restrict__ g2, const int* __restrict__ row_ptr,
    const int* __restrict__ csr_src, const float* __restrict__ dinv,
    const float* __restrict__ b2, float* __restrict__ out) {
    int i = blockIdx.x;
    int t = threadIdx.x;
    float acc = g2[(long)i * F_OUT + t];
    int beg = row_ptr[i], end = row_ptr[i + 1];
    for (int e = beg; e < end; ++e) {
        int j = csr_src[e];
        acc += g2[(long)j * F_OUT + t];
    }
    float v = dinv[i] * acc + b2[t];
    float m = v;
#pragma unroll
    for (int o = 32; o > 0; o >>= 1) m = fmaxf(m, __shfl_xor(m, o, 64));
    float ex = __expf(v - m);
    float s = ex;
#pragma unroll
    for (int o = 32; o > 0; o >>= 1) s += __shfl_xor(s, o, 64);
    out[(long)i * F_OUT + t] = v - m - __logf(s);
}

// ---------------- launch ----------------

extern "C" void kernel_launch(void* const* d_in, const int* in_sizes, int n_in,
                              void* d_out, int out_size, void* d_ws, size_t ws_size,
                              hipStream_t stream) {
    const float* x  = (const float*)d_in[0];
    const int* eidx = (const int*)d_in[1];   // [2, E]: row 0 = src, row 1 = dst
    const float* W1 = (const float*)d_in[2];
    const float* b1 = (const float*)d_in[3];
    const float* W2 = (const float*)d_in[4];
    const float* b2 = (const float*)d_in[5];
    float* out = (float*)d_out;
    const int* src = eidx;
    const int* dst = eidx + N_EDGES;

    // workspace layout (~110.4 MB total)
    char* base = (char*)d_ws;
    size_t off = 0;
    auto alloc = [&](size_t bytes) -> void* {
        void* p = base + off;
        off += (bytes + 255) & ~(size_t)255;
        return p;
    };
    int* deg      = (int*)alloc((size_t)N_NODES * 4);
    int* row_ptr  = (int*)alloc((size_t)(N_NODES + 1) * 4);
    int* cursor   = (int*)alloc((size_t)N_NODES * 4);
    float* dinv   = (float*)alloc((size_t)N_NODES * 4);
    int* bsum     = (int*)alloc((size_t)SCAN_NB * 4);
    int* csr_src  = (int*)alloc((size_t)N_EDGES * 4);
    float* g1     = (float*)alloc((size_t)N_NODES * F_HID * 4);
    float* h1     = (float*)alloc((size_t)N_NODES * F_HID * 4);
    float* g2     = g1;  // g1 dead after agg1; reuse for layer-2 scaled GEMM output

    hipMemsetAsync(deg, 0, (size_t)N_NODES * sizeof(int), stream);
    count_deg_kernel<<<(N_EDGES + 255) / 256, 256, 0, stream>>>(dst, deg, N_EDGES);
    // two-level scan (replaces 230us single-block scan; also computes dinv)
    block_sum_kernel<<<SCAN_NB, 256, 0, stream>>>(deg, bsum, N_NODES);
    scan_partials_kernel<<<1, 512, 0, stream>>>(bsum, SCAN_NB);
    scan_final_kernel<<<SCAN_NB, 256, 0, stream>>>(deg, bsum, row_ptr, cursor, dinv, N_NODES);
    fill_csr_kernel<<<(N_EDGES + 255) / 256, 256, 0, stream>>>(src, dst, cursor, csr_src, N_EDGES);

    // layer 1: g1 = (x @ W1) * dinv ; h1 = relu(dinv*(gather-sum g1) + b1)
    gemm_scale_kernel<<<dim3((N_NODES + BM - 1) / BM, F_HID / BN), 256, 0, stream>>>(
        x, W1, dinv, g1, N_NODES, F_IN, F_HID);
    agg1_kernel<<<N_NODES, F_HID, 0, stream>>>(g1, row_ptr, csr_src, dinv, b1, h1);

    // layer 2: g2 = (h1 @ W2) * dinv ; out = log_softmax(dinv*(gather-sum g2) + b2)
    gemm_scale_kernel<<<dim3((N_NODES + BM - 1) / BM, F_OUT / BN), 256, 0, stream>>>(
        h1, W2, dinv, g2, N_NODES, F_HID, F_OUT);
    agg2_lsm_kernel<<<N_NODES, F_OUT, 0, stream>>>(g2, row_ptr, csr_src, dinv, b2, out);
}

// Round 3
// 700.318 us; speedup vs baseline: 1.5654x; 1.2655x over previous
//
#include <hip/hip_runtime.h>
#include <cmath>

#define N_NODES 100000
#define N_EDGES 1600000
#define F_IN 512
#define F_HID 128
#define F_OUT 64

#define SCAN_NB ((N_NODES + 255) / 256)   // 391 blocks

typedef __attribute__((ext_vector_type(8))) short short8;
typedef __attribute__((ext_vector_type(4))) float float4v;

__device__ __forceinline__ unsigned short f2bf(float f) {
    unsigned u = __builtin_bit_cast(unsigned, f);
    u += 0x7FFFu + ((u >> 16) & 1u);   // RNE
    return (unsigned short)(u >> 16);
}
__device__ __forceinline__ float bf2f(unsigned short s) {
    unsigned u = ((unsigned)s) << 16;
    return __builtin_bit_cast(float, u);
}
__device__ __forceinline__ float lo_bf(unsigned u) {
    return __builtin_bit_cast(float, u << 16);
}
__device__ __forceinline__ float hi_bf(unsigned u) {
    return __builtin_bit_cast(float, u & 0xFFFF0000u);
}

// ---------------- CSR build ----------------

__global__ void count_deg_kernel(const int* __restrict__ dst, int* __restrict__ deg, int E) {
    int g = blockIdx.x * blockDim.x + threadIdx.x;
    if (g < E) atomicAdd(&deg[dst[g]], 1);
}

__global__ __launch_bounds__(256) void block_sum_kernel(const int* __restrict__ deg,
                                                        int* __restrict__ bsum, int n) {
    int g = blockIdx.x * 256 + threadIdx.x;
    int v = (g < n) ? deg[g] : 0;
    __shared__ int ws[4];
    int lane = threadIdx.x & 63;
    int w = threadIdx.x >> 6;
#pragma unroll
    for (int o = 32; o > 0; o >>= 1) v += __shfl_down(v, o, 64);
    if (lane == 0) ws[w] = v;
    __syncthreads();
    if (threadIdx.x == 0) bsum[blockIdx.x] = ws[0] + ws[1] + ws[2] + ws[3];
}

__global__ __launch_bounds__(512) void scan_partials_kernel(int* __restrict__ bsum, int nb) {
    __shared__ int t[512];
    int tid = threadIdx.x;
    int v = (tid < nb) ? bsum[tid] : 0;
    t[tid] = v;
    __syncthreads();
    for (int d = 1; d < 512; d <<= 1) {
        int u = (tid >= d) ? t[tid - d] : 0;
        __syncthreads();
        t[tid] += u;
        __syncthreads();
    }
    if (tid < nb) bsum[tid] = t[tid] - v;  // exclusive
}

__global__ __launch_bounds__(256) void scan_final_kernel(const int* __restrict__ deg,
                                                         const int* __restrict__ bsum,
                                                         int* __restrict__ row_ptr,
                                                         int* __restrict__ cursor,
                                                         float* __restrict__ dinv, int n) {
    __shared__ int t[256];
    int g = blockIdx.x * 256 + threadIdx.x;
    int tid = threadIdx.x;
    int v = (g < n) ? deg[g] : 0;
    t[tid] = v;
    __syncthreads();
    for (int d = 1; d < 256; d <<= 1) {
        int u = (tid >= d) ? t[tid - d] : 0;
        __syncthreads();
        t[tid] += u;
        __syncthreads();
    }
    int off = bsum[blockIdx.x] + t[tid] - v;
    if (g < n) {
        row_ptr[g] = off;
        cursor[g] = off;
        dinv[g] = rsqrtf((float)(v + 1));
    }
    if (g == n - 1) row_ptr[n] = off + v;
}

__global__ void fill_csr_kernel(const int* __restrict__ src, const int* __restrict__ dst,
                                int* __restrict__ cursor, int* __restrict__ csr_src, int E) {
    int g = blockIdx.x * blockDim.x + threadIdx.x;
    if (g < E) {
        int pos = atomicAdd(&cursor[dst[g]], 1);
        csr_src[pos] = src[g];
    }
}

// ---------------- W transpose+convert: Wt[n][k] bf16 (write-coalesced) ----------------

__global__ void transpose_w_kernel(const float* __restrict__ W1, const float* __restrict__ W2,
                                   unsigned short* __restrict__ Wt1,
                                   unsigned short* __restrict__ Wt2) {
    int g = blockIdx.x * 256 + threadIdx.x;
    if (g < F_HID * F_IN) {               // Wt1: [128][512]
        int n = g >> 9, k = g & 511;
        Wt1[g] = f2bf(W1[k * F_HID + n]);
    } else {
        int h = g - F_HID * F_IN;         // Wt2: [64][128]
        if (h < F_OUT * F_HID) {
            int n = h >> 7, k = h & 127;
            Wt2[h] = f2bf(W2[k * F_OUT + n]);
        }
    }
}

// ---------------- MFMA GEMM: out[r,:] = bf16( (A[r,:] @ W) * dinv[r] ) ----------------
// BM=128 (4 waves x 2 row-tiles of 16), BN = full output width, BK=32.
// sA[row][k], sB[col][k], both k-contiguous, rows padded to 40 shorts (2-way banks = free).

#define BKG 32
#define PAD 40

template <int BN, bool A_IS_BF16>
__global__ __launch_bounds__(256) void gemm_mfma_kernel(
    const void* __restrict__ Araw, const unsigned short* __restrict__ Wt,  // Wt[n][K]
    const float* __restrict__ dinv, unsigned short* __restrict__ out,      // bf16 [N][BN]
    int N, int K) {
    __shared__ unsigned short sA[128 * PAD];
    __shared__ unsigned short sB[BN * PAD];
    int tid = threadIdx.x;
    int lane = tid & 63;
    int wv = tid >> 6;
    int row0 = blockIdx.x * 128;
    int q8 = (lane >> 4) * 8;    // k-offset of this lane's fragment
    int l15 = lane & 15;

    float4v acc[2][BN / 16] = {};

    for (int k0 = 0; k0 < K; k0 += BKG) {
        // ---- stage A ----
        if (A_IS_BF16) {
            const unsigned short* A = (const unsigned short*)Araw;
            int cs = (tid & 3) * 8;
#pragma unroll
            for (int p = 0; p < 2; ++p) {
                int row = p * 64 + (tid >> 2);
                int gr = row0 + row;
                if (gr >= N) gr = N - 1;
                *(int4*)&sA[row * PAD + cs] = *(const int4*)&A[(size_t)gr * K + k0 + cs];
            }
        } else {
            const float* A = (const float*)Araw;
            int c4 = (tid & 7) * 4;
#pragma unroll
            for (int p = 0; p < 4; ++p) {
                int row = p * 32 + (tid >> 3);
                int gr = row0 + row;
                if (gr >= N) gr = N - 1;
                float4 v = *(const float4*)&A[(size_t)gr * K + k0 + c4];
                unsigned short b0 = f2bf(v.x), b1 = f2bf(v.y), b2 = f2bf(v.z), b3 = f2bf(v.w);
                unsigned pk0 = (unsigned)b0 | ((unsigned)b1 << 16);
                unsigned pk1 = (unsigned)b2 | ((unsigned)b3 << 16);
                *(uint2*)&sA[row * PAD + c4] = make_uint2(pk0, pk1);
            }
        }
        // ---- stage B ----
        {
            int cs = (tid & 3) * 8;
#pragma unroll
            for (int p = 0; p < BN / 64; ++p) {
                int n = p * 64 + (tid >> 2);
                *(int4*)&sB[n * PAD + cs] = *(const int4*)&Wt[(size_t)n * K + k0 + cs];
            }
        }
        __syncthreads();
        // ---- fragments + MFMA ----
        short8 a0 = *(const short8*)&sA[(wv * 32 + l15) * PAD + q8];
        short8 a1 = *(const short8*)&sA[(wv * 32 + 16 + l15) * PAD + q8];
#pragma unroll
        for (int ct = 0; ct < BN / 16; ++ct) {
            short8 b = *(const short8*)&sB[(ct * 16 + l15) * PAD + q8];
            acc[0][ct] = __builtin_amdgcn_mfma_f32_16x16x32_bf16(a0, b, acc[0][ct], 0, 0, 0);
            acc[1][ct] = __builtin_amdgcn_mfma_f32_16x16x32_bf16(a1, b, acc[1][ct], 0, 0, 0);
        }
        __syncthreads();
    }
    // ---- epilogue: scale by dinv[row], store bf16 ----
#pragma unroll
    for (int rt = 0; rt < 2; ++rt) {
#pragma unroll
        for (int reg = 0; reg < 4; ++reg) {
            int row = row0 + wv * 32 + rt * 16 + (lane >> 4) * 4 + reg;
            if (row < N) {
                float sc = dinv[row];
#pragma unroll
                for (int ct = 0; ct < BN / 16; ++ct) {
                    out[(size_t)row * BN + ct * 16 + l15] = f2bf(acc[rt][ct][reg] * sc);
                }
            }
        }
    }
}

// ---------------- aggregation (bf16 in, fp32 accumulate) ----------------
// h1[i,c] = relu(dinv[i]*(g1[i,c] + sum_{j in N(i)} g1[j,c]) + b1[c]); 128 cols as 64 x bf16x2
__global__ __launch_bounds__(256) void agg1_kernel(
    const unsigned int* __restrict__ g1, const int* __restrict__ row_ptr,
    const int* __restrict__ csr_src, const float* __restrict__ dinv,
    const float* __restrict__ b1, unsigned int* __restrict__ h1) {
    int node = blockIdx.x * 4 + (threadIdx.x >> 6);
    int lane = threadIdx.x & 63;
    if (node >= N_NODES) return;
    unsigned u = g1[(size_t)node * 64 + lane];
    float a0 = lo_bf(u), a1 = hi_bf(u);
    int e = row_ptr[node], end = row_ptr[node + 1];
    for (; e + 4 <= end; e += 4) {
        int j0 = csr_src[e], j1 = csr_src[e + 1], j2 = csr_src[e + 2], j3 = csr_src[e + 3];
        unsigned u0 = g1[(size_t)j0 * 64 + lane];
        unsigned u1 = g1[(size_t)j1 * 64 + lane];
        unsigned u2 = g1[(size_t)j2 * 64 + lane];
        unsigned u3 = g1[(size_t)j3 * 64 + lane];
        a0 += lo_bf(u0) + lo_bf(u1) + lo_bf(u2) + lo_bf(u3);
        a1 += hi_bf(u0) + hi_bf(u1) + hi_bf(u2) + hi_bf(u3);
    }
    for (; e < end; ++e) {
        unsigned u0 = g1[(size_t)csr_src[e] * 64 + lane];
        a0 += lo_bf(u0);
        a1 += hi_bf(u0);
    }
    float d = dinv[node];
    float v0 = fmaxf(d * a0 + b1[2 * lane], 0.0f);
    float v1 = fmaxf(d * a1 + b1[2 * lane + 1], 0.0f);
    h1[(size_t)node * 64 + lane] = (unsigned)f2bf(v0) | ((unsigned)f2bf(v1) << 16);
}

// out[i,:] = log_softmax(dinv[i]*(g2[i,:] + sum g2[j,:]) + b2); 64 cols, lane = class
__global__ __launch_bounds__(256) void agg2_lsm_kernel(
    const unsigned short* __restrict__ g2, const int* __restrict__ row_ptr,
    const int* __restrict__ csr_src, const float* __restrict__ dinv,
    const float* __restrict__ b2, float* __restrict__ out) {
    int node = blockIdx.x * 4 + (threadIdx.x >> 6);
    int lane = threadIdx.x & 63;
    if (node >= N_NODES) return;
    float a = bf2f(g2[(size_t)node * 64 + lane]);
    int e = row_ptr[node], end = row_ptr[node + 1];
    for (; e + 4 <= end; e += 4) {
        int j0 = csr_src[e], j1 = csr_src[e + 1], j2 = csr_src[e + 2], j3 = csr_src[e + 3];
        a += bf2f(g2[(size_t)j0 * 64 + lane]) + bf2f(g2[(size_t)j1 * 64 + lane]) +
             bf2f(g2[(size_t)j2 * 64 + lane]) + bf2f(g2[(size_t)j3 * 64 + lane]);
    }
    for (; e < end; ++e) a += bf2f(g2[(size_t)csr_src[e] * 64 + lane]);
    float v = dinv[node] * a + b2[lane];
    float m = v;
#pragma unroll
    for (int o = 32; o > 0; o >>= 1) m = fmaxf(m, __shfl_xor(m, o, 64));
    float ex = __expf(v - m);
    float s = ex;
#pragma unroll
    for (int o = 32; o > 0; o >>= 1) s += __shfl_xor(s, o, 64);
    out[(size_t)node * 64 + lane] = v - m - __logf(s);
}

// ---------------- launch ----------------

extern "C" void kernel_launch(void* const* d_in, const int* in_sizes, int n_in,
                              void* d_out, int out_size, void* d_ws, size_t ws_size,
                              hipStream_t stream) {
    const float* x  = (const float*)d_in[0];
    const int* eidx = (const int*)d_in[1];
    const float* W1 = (const float*)d_in[2];
    const float* b1 = (const float*)d_in[3];
    const float* W2 = (const float*)d_in[4];
    const float* b2 = (const float*)d_in[5];
    float* out = (float*)d_out;
    const int* src = eidx;
    const int* dst = eidx + N_EDGES;

    char* base = (char*)d_ws;
    size_t off = 0;
    auto alloc = [&](size_t bytes) -> void* {
        void* p = base + off;
        off += (bytes + 255) & ~(size_t)255;
        return p;
    };
    int* deg      = (int*)alloc((size_t)N_NODES * 4);
    int* row_ptr  = (int*)alloc((size_t)(N_NODES + 1) * 4);
    int* cursor   = (int*)alloc((size_t)N_NODES * 4);
    float* dinv   = (float*)alloc((size_t)N_NODES * 4);
    int* bsum     = (int*)alloc((size_t)SCAN_NB * 4);
    int* csr_src  = (int*)alloc((size_t)N_EDGES * 4);
    unsigned short* Wt1 = (unsigned short*)alloc((size_t)F_HID * F_IN * 2);
    unsigned short* Wt2 = (unsigned short*)alloc((size_t)F_OUT * F_HID * 2);
    unsigned short* g1  = (unsigned short*)alloc((size_t)N_NODES * F_HID * 2);
    unsigned short* h1  = (unsigned short*)alloc((size_t)N_NODES * F_HID * 2);
    unsigned short* g2  = g1;  // g1 dead after agg1

    hipMemsetAsync(deg, 0, (size_t)N_NODES * sizeof(int), stream);
    count_deg_kernel<<<(N_EDGES + 255) / 256, 256, 0, stream>>>(dst, deg, N_EDGES);
    block_sum_kernel<<<SCAN_NB, 256, 0, stream>>>(deg, bsum, N_NODES);
    scan_partials_kernel<<<1, 512, 0, stream>>>(bsum, SCAN_NB);
    scan_final_kernel<<<SCAN_NB, 256, 0, stream>>>(deg, bsum, row_ptr, cursor, dinv, N_NODES);
    fill_csr_kernel<<<(N_EDGES + 255) / 256, 256, 0, stream>>>(src, dst, cursor, csr_src, N_EDGES);
    transpose_w_kernel<<<(F_HID * F_IN + F_OUT * F_HID + 255) / 256, 256, 0, stream>>>(
        W1, W2, Wt1, Wt2);

    int gblocks = (N_NODES + 127) / 128;  // 782
    // layer 1: g1 = bf16((x @ W1) * dinv)
    gemm_mfma_kernel<F_HID, false><<<gblocks, 256, 0, stream>>>(
        (const void*)x, Wt1, dinv, g1, N_NODES, F_IN);
    agg1_kernel<<<(N_NODES + 3) / 4, 256, 0, stream>>>(
        (const unsigned int*)g1, row_ptr, csr_src, dinv, b1, (unsigned int*)h1);

    // layer 2: g2 = bf16((h1 @ W2) * dinv)
    gemm_mfma_kernel<F_OUT, true><<<gblocks, 256, 0, stream>>>(
        (const void*)h1, Wt2, dinv, g2, N_NODES, F_HID);
    agg2_lsm_kernel<<<(N_NODES + 3) / 4, 256, 0, stream>>>(
        g2, row_ptr, csr_src, dinv, b2, out);
}

// Round 4
// 678.982 us; speedup vs baseline: 1.6146x; 1.0314x over previous
//
#include <hip/hip_runtime.h>
#include <cmath>

#define N_NODES 100000
#define N_EDGES 1600000
#define F_IN 512
#define F_HID 128
#define F_OUT 64

#define SCAN_NB ((N_NODES + 255) / 256)   // 391 blocks

typedef __attribute__((ext_vector_type(8))) short short8;
typedef __attribute__((ext_vector_type(4))) float float4v;

__device__ __forceinline__ unsigned short f2bf(float f) {
    unsigned u = __builtin_bit_cast(unsigned, f);
    u += 0x7FFFu + ((u >> 16) & 1u);   // RNE
    return (unsigned short)(u >> 16);
}
__device__ __forceinline__ float bf2f(unsigned short s) {
    unsigned u = ((unsigned)s) << 16;
    return __builtin_bit_cast(float, u);
}
__device__ __forceinline__ float lo_bf(unsigned u) {
    return __builtin_bit_cast(float, u << 16);
}
__device__ __forceinline__ float hi_bf(unsigned u) {
    return __builtin_bit_cast(float, u & 0xFFFF0000u);
}

// ---------------- CSR build ----------------

__global__ void count_deg_kernel(const int* __restrict__ dst, int* __restrict__ deg, int E) {
    int g = blockIdx.x * blockDim.x + threadIdx.x;
    if (g < E) atomicAdd(&deg[dst[g]], 1);
}

__global__ __launch_bounds__(256) void block_sum_kernel(const int* __restrict__ deg,
                                                        int* __restrict__ bsum, int n) {
    int g = blockIdx.x * 256 + threadIdx.x;
    int v = (g < n) ? deg[g] : 0;
    __shared__ int ws[4];
    int lane = threadIdx.x & 63;
    int w = threadIdx.x >> 6;
#pragma unroll
    for (int o = 32; o > 0; o >>= 1) v += __shfl_down(v, o, 64);
    if (lane == 0) ws[w] = v;
    __syncthreads();
    if (threadIdx.x == 0) bsum[blockIdx.x] = ws[0] + ws[1] + ws[2] + ws[3];
}

__global__ __launch_bounds__(512) void scan_partials_kernel(int* __restrict__ bsum, int nb) {
    __shared__ int t[512];
    int tid = threadIdx.x;
    int v = (tid < nb) ? bsum[tid] : 0;
    t[tid] = v;
    __syncthreads();
    for (int d = 1; d < 512; d <<= 1) {
        int u = (tid >= d) ? t[tid - d] : 0;
        __syncthreads();
        t[tid] += u;
        __syncthreads();
    }
    if (tid < nb) bsum[tid] = t[tid] - v;  // exclusive
}

__global__ __launch_bounds__(256) void scan_final_kernel(const int* __restrict__ deg,
                                                         const int* __restrict__ bsum,
                                                         int* __restrict__ row_ptr,
                                                         int* __restrict__ cursor,
                                                         float* __restrict__ dinv, int n) {
    __shared__ int t[256];
    int g = blockIdx.x * 256 + threadIdx.x;
    int tid = threadIdx.x;
    int v = (g < n) ? deg[g] : 0;
    t[tid] = v;
    __syncthreads();
    for (int d = 1; d < 256; d <<= 1) {
        int u = (tid >= d) ? t[tid - d] : 0;
        __syncthreads();
        t[tid] += u;
        __syncthreads();
    }
    int off = bsum[blockIdx.x] + t[tid] - v;
    if (g < n) {
        row_ptr[g] = off;
        cursor[g] = off;
        dinv[g] = rsqrtf((float)(v + 1));
    }
    if (g == n - 1) row_ptr[n] = off + v;
}

__global__ void fill_csr_kernel(const int* __restrict__ src, const int* __restrict__ dst,
                                int* __restrict__ cursor, int* __restrict__ csr_src, int E) {
    int g = blockIdx.x * blockDim.x + threadIdx.x;
    if (g < E) {
        int pos = atomicAdd(&cursor[dst[g]], 1);
        csr_src[pos] = src[g];
    }
}

// ---------------- W transpose+convert: Wt[n][k] bf16 ----------------

__global__ void transpose_w_kernel(const float* __restrict__ W1, const float* __restrict__ W2,
                                   unsigned short* __restrict__ Wt1,
                                   unsigned short* __restrict__ Wt2) {
    int g = blockIdx.x * 256 + threadIdx.x;
    if (g < F_HID * F_IN) {               // Wt1: [128][512]
        int n = g >> 9, k = g & 511;
        Wt1[g] = f2bf(W1[k * F_HID + n]);
    } else {
        int h = g - F_HID * F_IN;         // Wt2: [64][128]
        if (h < F_OUT * F_HID) {
            int n = h >> 7, k = h & 127;
            Wt2[h] = f2bf(W2[k * F_OUT + n]);
        }
    }
}

// ---------------- barrier-free direct-load MFMA GEMM ----------------
// out[r,:] = bf16((A[r,:] @ Wt^T) * dinv[r]).  Wt[n][k] bf16, L2-resident.
// One wave owns 32 rows x BN cols; A and B fragments loaded straight from
// global into registers (16B/lane contiguous); NO LDS, NO __syncthreads —
// the compiler interleaves next-k loads under current-k MFMAs via vmcnt.

template <int BN, int K, bool A_BF16>
__global__ __launch_bounds__(256) void gemm_direct_kernel(
    const void* __restrict__ Araw, const unsigned short* __restrict__ Wt,
    const float* __restrict__ dinv, unsigned short* __restrict__ out, int N) {
    int lane = threadIdx.x & 63;
    int wv = threadIdx.x >> 6;
    int row0 = blockIdx.x * 128 + wv * 32;
    if (row0 >= N) return;                 // no barriers in kernel: safe
    int l15 = lane & 15;
    int q = lane >> 4;                     // quad id 0..3
    int q8 = q * 8;                        // k-offset of this lane's fragment
    int r0 = row0 + l15;
    int r1 = r0 + 16;
    int r0c = r0 < N ? r0 : N - 1;
    int r1c = r1 < N ? r1 : N - 1;

    float4v acc[2][BN / 16] = {};

#pragma unroll 2
    for (int k0 = 0; k0 < K; k0 += 32) {
        short8 a0, a1;
        if (A_BF16) {
            const unsigned short* A = (const unsigned short*)Araw;
            a0 = *(const short8*)&A[(size_t)r0c * K + k0 + q8];
            a1 = *(const short8*)&A[(size_t)r1c * K + k0 + q8];
        } else {
            const float* A = (const float*)Araw;
            float4 x0 = *(const float4*)&A[(size_t)r0c * K + k0 + q8];
            float4 x1 = *(const float4*)&A[(size_t)r0c * K + k0 + q8 + 4];
            float4 y0 = *(const float4*)&A[(size_t)r1c * K + k0 + q8];
            float4 y1 = *(const float4*)&A[(size_t)r1c * K + k0 + q8 + 4];
            a0 = short8{(short)f2bf(x0.x), (short)f2bf(x0.y), (short)f2bf(x0.z), (short)f2bf(x0.w),
                        (short)f2bf(x1.x), (short)f2bf(x1.y), (short)f2bf(x1.z), (short)f2bf(x1.w)};
            a1 = short8{(short)f2bf(y0.x), (short)f2bf(y0.y), (short)f2bf(y0.z), (short)f2bf(y0.w),
                        (short)f2bf(y1.x), (short)f2bf(y1.y), (short)f2bf(y1.z), (short)f2bf(y1.w)};
        }
#pragma unroll
        for (int ct = 0; ct < BN / 16; ++ct) {
            short8 b = *(const short8*)&Wt[(size_t)(ct * 16 + l15) * K + k0 + q8];
            acc[0][ct] = __builtin_amdgcn_mfma_f32_16x16x32_bf16(a0, b, acc[0][ct], 0, 0, 0);
            acc[1][ct] = __builtin_amdgcn_mfma_f32_16x16x32_bf16(a1, b, acc[1][ct], 0, 0, 0);
        }
    }
    // epilogue: C/D layout col=lane&15, row=q*4+reg; scale by dinv, store bf16
#pragma unroll
    for (int rt = 0; rt < 2; ++rt) {
#pragma unroll
        for (int reg = 0; reg < 4; ++reg) {
            int row = row0 + rt * 16 + q * 4 + reg;
            if (row < N) {
                float sc = dinv[row];
#pragma unroll
                for (int ct = 0; ct < BN / 16; ++ct) {
                    out[(size_t)row * BN + ct * 16 + l15] = f2bf(acc[rt][ct][reg] * sc);
                }
            }
        }
    }
}

// ---------------- aggregation (bf16 in, fp32 accumulate) ----------------
__global__ __launch_bounds__(256) void agg1_kernel(
    const unsigned int* __restrict__ g1, const int* __restrict__ row_ptr,
    const int* __restrict__ csr_src, const float* __restrict__ dinv,
    const float* __restrict__ b1, unsigned int* __restrict__ h1) {
    int node = blockIdx.x * 4 + (threadIdx.x >> 6);
    int lane = threadIdx.x & 63;
    if (node >= N_NODES) return;
    unsigned u = g1[(size_t)node * 64 + lane];
    float a0 = lo_bf(u), a1 = hi_bf(u);
    int e = row_ptr[node], end = row_ptr[node + 1];
    for (; e + 4 <= end; e += 4) {
        int j0 = csr_src[e], j1 = csr_src[e + 1], j2 = csr_src[e + 2], j3 = csr_src[e + 3];
        unsigned u0 = g1[(size_t)j0 * 64 + lane];
        unsigned u1 = g1[(size_t)j1 * 64 + lane];
        unsigned u2 = g1[(size_t)j2 * 64 + lane];
        unsigned u3 = g1[(size_t)j3 * 64 + lane];
        a0 += lo_bf(u0) + lo_bf(u1) + lo_bf(u2) + lo_bf(u3);
        a1 += hi_bf(u0) + hi_bf(u1) + hi_bf(u2) + hi_bf(u3);
    }
    for (; e < end; ++e) {
        unsigned u0 = g1[(size_t)csr_src[e] * 64 + lane];
        a0 += lo_bf(u0);
        a1 += hi_bf(u0);
    }
    float d = dinv[node];
    float v0 = fmaxf(d * a0 + b1[2 * lane], 0.0f);
    float v1 = fmaxf(d * a1 + b1[2 * lane + 1], 0.0f);
    h1[(size_t)node * 64 + lane] = (unsigned)f2bf(v0) | ((unsigned)f2bf(v1) << 16);
}

__global__ __launch_bounds__(256) void agg2_lsm_kernel(
    const unsigned short* __restrict__ g2, const int* __restrict__ row_ptr,
    const int* __restrict__ csr_src, const float* __restrict__ dinv,
    const float* __restrict__ b2, float* __restrict__ out) {
    int node = blockIdx.x * 4 + (threadIdx.x >> 6);
    int lane = threadIdx.x & 63;
    if (node >= N_NODES) return;
    float a = bf2f(g2[(size_t)node * 64 + lane]);
    int e = row_ptr[node], end = row_ptr[node + 1];
    for (; e + 4 <= end; e += 4) {
        int j0 = csr_src[e], j1 = csr_src[e + 1], j2 = csr_src[e + 2], j3 = csr_src[e + 3];
        a += bf2f(g2[(size_t)j0 * 64 + lane]) + bf2f(g2[(size_t)j1 * 64 + lane]) +
             bf2f(g2[(size_t)j2 * 64 + lane]) + bf2f(g2[(size_t)j3 * 64 + lane]);
    }
    for (; e < end; ++e) a += bf2f(g2[(size_t)csr_src[e] * 64 + lane]);
    float v = dinv[node] * a + b2[lane];
    float m = v;
#pragma unroll
    for (int o = 32; o > 0; o >>= 1) m = fmaxf(m, __shfl_xor(m, o, 64));
    float ex = __expf(v - m);
    float s = ex;
#pragma unroll
    for (int o = 32; o > 0; o >>= 1) s += __shfl_xor(s, o, 64);
    out[(size_t)node * 64 + lane] = v - m - __logf(s);
}

// ---------------- launch ----------------

extern "C" void kernel_launch(void* const* d_in, const int* in_sizes, int n_in,
                              void* d_out, int out_size, void* d_ws, size_t ws_size,
                              hipStream_t stream) {
    const float* x  = (const float*)d_in[0];
    const int* eidx = (const int*)d_in[1];
    const float* W1 = (const float*)d_in[2];
    const float* b1 = (const float*)d_in[3];
    const float* W2 = (const float*)d_in[4];
    const float* b2 = (const float*)d_in[5];
    float* out = (float*)d_out;
    const int* src = eidx;
    const int* dst = eidx + N_EDGES;

    char* base = (char*)d_ws;
    size_t off = 0;
    auto alloc = [&](size_t bytes) -> void* {
        void* p = base + off;
        off += (bytes + 255) & ~(size_t)255;
        return p;
    };
    int* deg      = (int*)alloc((size_t)N_NODES * 4);
    int* row_ptr  = (int*)alloc((size_t)(N_NODES + 1) * 4);
    int* cursor   = (int*)alloc((size_t)N_NODES * 4);
    float* dinv   = (float*)alloc((size_t)N_NODES * 4);
    int* bsum     = (int*)alloc((size_t)SCAN_NB * 4);
    int* csr_src  = (int*)alloc((size_t)N_EDGES * 4);
    unsigned short* Wt1 = (unsigned short*)alloc((size_t)F_HID * F_IN * 2);
    unsigned short* Wt2 = (unsigned short*)alloc((size_t)F_OUT * F_HID * 2);
    unsigned short* g1  = (unsigned short*)alloc((size_t)N_NODES * F_HID * 2);
    unsigned short* h1  = (unsigned short*)alloc((size_t)N_NODES * F_HID * 2);
    unsigned short* g2  = g1;  // g1 dead after agg1

    hipMemsetAsync(deg, 0, (size_t)N_NODES * sizeof(int), stream);
    count_deg_kernel<<<(N_EDGES + 255) / 256, 256, 0, stream>>>(dst, deg, N_EDGES);
    block_sum_kernel<<<SCAN_NB, 256, 0, stream>>>(deg, bsum, N_NODES);
    scan_partials_kernel<<<1, 512, 0, stream>>>(bsum, SCAN_NB);
    scan_final_kernel<<<SCAN_NB, 256, 0, stream>>>(deg, bsum, row_ptr, cursor, dinv, N_NODES);
    fill_csr_kernel<<<(N_EDGES + 255) / 256, 256, 0, stream>>>(src, dst, cursor, csr_src, N_EDGES);
    transpose_w_kernel<<<(F_HID * F_IN + F_OUT * F_HID + 255) / 256, 256, 0, stream>>>(
        W1, W2, Wt1, Wt2);

    int gblocks = (N_NODES + 127) / 128;  // 782
    // layer 1: g1 = bf16((x @ W1) * dinv)
    gemm_direct_kernel<F_HID, F_IN, false><<<gblocks, 256, 0, stream>>>(
        (const void*)x, Wt1, dinv, g1, N_NODES);
    agg1_kernel<<<(N_NODES + 3) / 4, 256, 0, stream>>>(
        (const unsigned int*)g1, row_ptr, csr_src, dinv, b1, (unsigned int*)h1);

    // layer 2: g2 = bf16((h1 @ W2) * dinv)
    gemm_direct_kernel<F_OUT, F_HID, true><<<gblocks, 256, 0, stream>>>(
        (const void*)h1, Wt2, dinv, g2, N_NODES);
    agg2_lsm_kernel<<<(N_NODES + 3) / 4, 256, 0, stream>>>(
        g2, row_ptr, csr_src, dinv, b2, out);
}

// Round 5
// 660.754 us; speedup vs baseline: 1.6591x; 1.0276x over previous
//
#include <hip/hip_runtime.h>
#include <cmath>

#define N_NODES 100000
#define N_EDGES 1600000
#define F_IN 512
#define F_HID 128
#define F_OUT 64

#define SCAN_NB ((N_NODES + 255) / 256)   // 391 blocks

// ---- bucketed CSR-build params ----
#define BK_SHIFT 10                        // 1024 nodes per bucket
#define NBUK ((N_NODES + 1023) >> 10)      // 98 buckets
#define SCAP 24576                         // staging capacity/bucket (mean 16327, +65 sigma)
#define LSLOT 64                           // LDS slots per bucket
#define NBLK_A 128                         // partition blocks
#define OV_CAP 4096                        // global overflow records

typedef __attribute__((ext_vector_type(8))) short short8;
typedef __attribute__((ext_vector_type(4))) float float4v;

__device__ __forceinline__ unsigned short f2bf(float f) {
    unsigned u = __builtin_bit_cast(unsigned, f);
    u += 0x7FFFu + ((u >> 16) & 1u);   // RNE
    return (unsigned short)(u >> 16);
}
__device__ __forceinline__ float bf2f(unsigned short s) {
    unsigned u = ((unsigned)s) << 16;
    return __builtin_bit_cast(float, u);
}
__device__ __forceinline__ float lo_bf(unsigned u) {
    return __builtin_bit_cast(float, u << 16);
}
__device__ __forceinline__ float hi_bf(unsigned u) {
    return __builtin_bit_cast(float, u & 0xFFFF0000u);
}

// ---------------- partition: edges -> per-bucket staging (+deg count fused) ----------------
// LDS multisplit: drain only full 16-rec (64B) groups so staging writes are
// dense full lines appended by per-bucket global cursors. One CSR line is
// later written by exactly one block (one XCD L2) -> no write amplification.
__global__ __launch_bounds__(256) void partition_kernel(
    const int* __restrict__ src, const int* __restrict__ dst,
    int* __restrict__ deg, unsigned* __restrict__ staging, int* __restrict__ gcur,
    unsigned long long* __restrict__ ovbuf, int* __restrict__ ovcnt) {
    __shared__ unsigned buf[NBUK][LSLOT];
    __shared__ int cnt[NBUK];
    int tid = threadIdx.x;
    for (int b = tid; b < NBUK; b += 256) cnt[b] = 0;
    __syncthreads();
    const int PER = (N_EDGES + NBLK_A - 1) / NBLK_A;   // 12500
    int e0 = blockIdx.x * PER;
    int e1 = min(e0 + PER, N_EDGES);
    for (int base = e0; base < e1; base += 1024) {
#pragma unroll
        for (int t = 0; t < 4; ++t) {
            int e = base + t * 256 + tid;
            if (e < e1) {
                int d = dst[e];
                int s = src[e];
                atomicAdd(&deg[d], 1);
                int b = d >> BK_SHIFT;
                unsigned rec = (unsigned)s | ((unsigned)(d & 1023) << 17);
                int slot = atomicAdd(&cnt[b], 1);
                if (slot < LSLOT) {
                    buf[b][slot] = rec;
                } else {  // rare LDS overflow: spill (src,dst) to global list
                    int op = atomicAdd(ovcnt, 1);
                    if (op < OV_CAP)
                        ovbuf[op] = ((unsigned long long)(unsigned)d << 32) | (unsigned)s;
                }
            }
        }
        __syncthreads();
        // drain full 16-record groups, carry remainder (<16)
        for (int b = tid; b < NBUK; b += 256) {
            int c = min(cnt[b], LSLOT);
            int full = c & ~15;
            if (full > 0) {
                int pos = atomicAdd(&gcur[b], full);
                if (pos + full <= SCAP) {
                    unsigned* dp = &staging[(size_t)b * SCAP + pos];
                    for (int i = 0; i < full; ++i) dp[i] = buf[b][i];
                }
                for (int i = 0; i < c - full; ++i) buf[b][i] = buf[b][full + i];
            }
            cnt[b] = c - full;
        }
        __syncthreads();
    }
    // final flush of remainders
    for (int b = tid; b < NBUK; b += 256) {
        int c = cnt[b];
        if (c > 0) {
            int pos = atomicAdd(&gcur[b], c);
            if (pos + c <= SCAP)
                for (int i = 0; i < c; ++i) staging[(size_t)b * SCAP + pos + i] = buf[b][i];
        }
    }
}

// ---------------- fill: one block per bucket -> single-XCD-local CSR scatter ----------------
__global__ __launch_bounds__(256) void fill_kernel(
    const unsigned* __restrict__ staging, const int* __restrict__ gcur,
    int* __restrict__ cursor, int* __restrict__ csr_src,
    const unsigned long long* __restrict__ ovbuf, const int* __restrict__ ovcnt) {
    int b = blockIdx.x;
    int node0 = b << BK_SHIFT;
    int n = gcur[b];
    if (n > SCAP) n = SCAP;
    const unsigned* sp = &staging[(size_t)b * SCAP];
    for (int i = threadIdx.x; i < n; i += 256) {
        unsigned rec = sp[i];
        int s = (int)(rec & 0x1FFFFu);
        int d = node0 + (int)(rec >> 17);
        int pos = atomicAdd(&cursor[d], 1);
        csr_src[pos] = s;
    }
    int oc = *ovcnt;
    if (oc > OV_CAP) oc = OV_CAP;
    for (int i = threadIdx.x; i < oc; i += 256) {
        unsigned long long r = ovbuf[i];
        int d = (int)(r >> 32);
        if ((d >> BK_SHIFT) == b) {
            int pos = atomicAdd(&cursor[d], 1);
            csr_src[pos] = (int)(r & 0xffffffffu);
        }
    }
}

// ---------------- scans ----------------

__global__ __launch_bounds__(256) void block_sum_kernel(const int* __restrict__ deg,
                                                        int* __restrict__ bsum, int n) {
    int g = blockIdx.x * 256 + threadIdx.x;
    int v = (g < n) ? deg[g] : 0;
    __shared__ int ws[4];
    int lane = threadIdx.x & 63;
    int w = threadIdx.x >> 6;
#pragma unroll
    for (int o = 32; o > 0; o >>= 1) v += __shfl_down(v, o, 64);
    if (lane == 0) ws[w] = v;
    __syncthreads();
    if (threadIdx.x == 0) bsum[blockIdx.x] = ws[0] + ws[1] + ws[2] + ws[3];
}

__global__ __launch_bounds__(512) void scan_partials_kernel(int* __restrict__ bsum, int nb) {
    __shared__ int t[512];
    int tid = threadIdx.x;
    int v = (tid < nb) ? bsum[tid] : 0;
    t[tid] = v;
    __syncthreads();
    for (int d = 1; d < 512; d <<= 1) {
        int u = (tid >= d) ? t[tid - d] : 0;
        __syncthreads();
        t[tid] += u;
        __syncthreads();
    }
    if (tid < nb) bsum[tid] = t[tid] - v;  // exclusive
}

__global__ __launch_bounds__(256) void scan_final_kernel(const int* __restrict__ deg,
                                                         const int* __restrict__ bsum,
                                                         int* __restrict__ row_ptr,
                                                         int* __restrict__ cursor,
                                                         float* __restrict__ dinv, int n) {
    __shared__ int t[256];
    int g = blockIdx.x * 256 + threadIdx.x;
    int tid = threadIdx.x;
    int v = (g < n) ? deg[g] : 0;
    t[tid] = v;
    __syncthreads();
    for (int d = 1; d < 256; d <<= 1) {
        int u = (tid >= d) ? t[tid - d] : 0;
        __syncthreads();
        t[tid] += u;
        __syncthreads();
    }
    int off = bsum[blockIdx.x] + t[tid] - v;
    if (g < n) {
        row_ptr[g] = off;
        cursor[g] = off;
        dinv[g] = rsqrtf((float)(v + 1));
    }
    if (g == n - 1) row_ptr[n] = off + v;
}

// ---------------- W transpose+convert: Wt[n][k] bf16 ----------------

__global__ void transpose_w_kernel(const float* __restrict__ W1, const float* __restrict__ W2,
                                   unsigned short* __restrict__ Wt1,
                                   unsigned short* __restrict__ Wt2) {
    int g = blockIdx.x * 256 + threadIdx.x;
    if (g < F_HID * F_IN) {               // Wt1: [128][512]
        int n = g >> 9, k = g & 511;
        Wt1[g] = f2bf(W1[k * F_HID + n]);
    } else {
        int h = g - F_HID * F_IN;         // Wt2: [64][128]
        if (h < F_OUT * F_HID) {
            int n = h >> 7, k = h & 127;
            Wt2[h] = f2bf(W2[k * F_OUT + n]);
        }
    }
}

// ---------------- barrier-free direct-load MFMA GEMM (unchanged from R4) ----------------

template <int BN, int K, bool A_BF16>
__global__ __launch_bounds__(256) void gemm_direct_kernel(
    const void* __restrict__ Araw, const unsigned short* __restrict__ Wt,
    const float* __restrict__ dinv, unsigned short* __restrict__ out, int N) {
    int lane = threadIdx.x & 63;
    int wv = threadIdx.x >> 6;
    int row0 = blockIdx.x * 128 + wv * 32;
    if (row0 >= N) return;                 // no barriers in kernel: safe
    int l15 = lane & 15;
    int q = lane >> 4;
    int q8 = q * 8;
    int r0 = row0 + l15;
    int r1 = r0 + 16;
    int r0c = r0 < N ? r0 : N - 1;
    int r1c = r1 < N ? r1 : N - 1;

    float4v acc[2][BN / 16] = {};

#pragma unroll 2
    for (int k0 = 0; k0 < K; k0 += 32) {
        short8 a0, a1;
        if (A_BF16) {
            const unsigned short* A = (const unsigned short*)Araw;
            a0 = *(const short8*)&A[(size_t)r0c * K + k0 + q8];
            a1 = *(const short8*)&A[(size_t)r1c * K + k0 + q8];
        } else {
            const float* A = (const float*)Araw;
            float4 x0 = *(const float4*)&A[(size_t)r0c * K + k0 + q8];
            float4 x1 = *(const float4*)&A[(size_t)r0c * K + k0 + q8 + 4];
            float4 y0 = *(const float4*)&A[(size_t)r1c * K + k0 + q8];
            float4 y1 = *(const float4*)&A[(size_t)r1c * K + k0 + q8 + 4];
            a0 = short8{(short)f2bf(x0.x), (short)f2bf(x0.y), (short)f2bf(x0.z), (short)f2bf(x0.w),
                        (short)f2bf(x1.x), (short)f2bf(x1.y), (short)f2bf(x1.z), (short)f2bf(x1.w)};
            a1 = short8{(short)f2bf(y0.x), (short)f2bf(y0.y), (short)f2bf(y0.z), (short)f2bf(y0.w),
                        (short)f2bf(y1.x), (short)f2bf(y1.y), (short)f2bf(y1.z), (short)f2bf(y1.w)};
        }
#pragma unroll
        for (int ct = 0; ct < BN / 16; ++ct) {
            short8 b = *(const short8*)&Wt[(size_t)(ct * 16 + l15) * K + k0 + q8];
            acc[0][ct] = __builtin_amdgcn_mfma_f32_16x16x32_bf16(a0, b, acc[0][ct], 0, 0, 0);
            acc[1][ct] = __builtin_amdgcn_mfma_f32_16x16x32_bf16(a1, b, acc[1][ct], 0, 0, 0);
        }
    }
#pragma unroll
    for (int rt = 0; rt < 2; ++rt) {
#pragma unroll
        for (int reg = 0; reg < 4; ++reg) {
            int row = row0 + rt * 16 + q * 4 + reg;
            if (row < N) {
                float sc = dinv[row];
#pragma unroll
                for (int ct = 0; ct < BN / 16; ++ct) {
                    out[(size_t)row * BN + ct * 16 + l15] = f2bf(acc[rt][ct][reg] * sc);
                }
            }
        }
    }
}

// ---------------- aggregation (bf16 in, fp32 accumulate) ----------------
__global__ __launch_bounds__(256) void agg1_kernel(
    const unsigned int* __restrict__ g1, const int* __restrict__ row_ptr,
    const int* __restrict__ csr_src, const float* __restrict__ dinv,
    const float* __restrict__ b1, unsigned int* __restrict__ h1) {
    int node = blockIdx.x * 4 + (threadIdx.x >> 6);
    int lane = threadIdx.x & 63;
    if (node >= N_NODES) return;
    unsigned u = g1[(size_t)node * 64 + lane];
    float a0 = lo_bf(u), a1 = hi_bf(u);
    int e = row_ptr[node], end = row_ptr[node + 1];
    for (; e + 4 <= end; e += 4) {
        int j0 = csr_src[e], j1 = csr_src[e + 1], j2 = csr_src[e + 2], j3 = csr_src[e + 3];
        unsigned u0 = g1[(size_t)j0 * 64 + lane];
        unsigned u1 = g1[(size_t)j1 * 64 + lane];
        unsigned u2 = g1[(size_t)j2 * 64 + lane];
        unsigned u3 = g1[(size_t)j3 * 64 + lane];
        a0 += lo_bf(u0) + lo_bf(u1) + lo_bf(u2) + lo_bf(u3);
        a1 += hi_bf(u0) + hi_bf(u1) + hi_bf(u2) + hi_bf(u3);
    }
    for (; e < end; ++e) {
        unsigned u0 = g1[(size_t)csr_src[e] * 64 + lane];
        a0 += lo_bf(u0);
        a1 += hi_bf(u0);
    }
    float d = dinv[node];
    float v0 = fmaxf(d * a0 + b1[2 * lane], 0.0f);
    float v1 = fmaxf(d * a1 + b1[2 * lane + 1], 0.0f);
    h1[(size_t)node * 64 + lane] = (unsigned)f2bf(v0) | ((unsigned)f2bf(v1) << 16);
}

__global__ __launch_bounds__(256) void agg2_lsm_kernel(
    const unsigned short* __restrict__ g2, const int* __restrict__ row_ptr,
    const int* __restrict__ csr_src, const float* __restrict__ dinv,
    const float* __restrict__ b2, float* __restrict__ out) {
    int node = blockIdx.x * 4 + (threadIdx.x >> 6);
    int lane = threadIdx.x & 63;
    if (node >= N_NODES) return;
    float a = bf2f(g2[(size_t)node * 64 + lane]);
    int e = row_ptr[node], end = row_ptr[node + 1];
    for (; e + 4 <= end; e += 4) {
        int j0 = csr_src[e], j1 = csr_src[e + 1], j2 = csr_src[e + 2], j3 = csr_src[e + 3];
        a += bf2f(g2[(size_t)j0 * 64 + lane]) + bf2f(g2[(size_t)j1 * 64 + lane]) +
             bf2f(g2[(size_t)j2 * 64 + lane]) + bf2f(g2[(size_t)j3 * 64 + lane]);
    }
    for (; e < end; ++e) a += bf2f(g2[(size_t)csr_src[e] * 64 + lane]);
    float v = dinv[node] * a + b2[lane];
    float m = v;
#pragma unroll
    for (int o = 32; o > 0; o >>= 1) m = fmaxf(m, __shfl_xor(m, o, 64));
    float ex = __expf(v - m);
    float s = ex;
#pragma unroll
    for (int o = 32; o > 0; o >>= 1) s += __shfl_xor(s, o, 64);
    out[(size_t)node * 64 + lane] = v - m - __logf(s);
}

// ---------------- launch ----------------

extern "C" void kernel_launch(void* const* d_in, const int* in_sizes, int n_in,
                              void* d_out, int out_size, void* d_ws, size_t ws_size,
                              hipStream_t stream) {
    const float* x  = (const float*)d_in[0];
    const int* eidx = (const int*)d_in[1];
    const float* W1 = (const float*)d_in[2];
    const float* b1 = (const float*)d_in[3];
    const float* W2 = (const float*)d_in[4];
    const float* b2 = (const float*)d_in[5];
    float* out = (float*)d_out;
    const int* src = eidx;
    const int* dst = eidx + N_EDGES;

    char* base = (char*)d_ws;
    size_t off = 0;
    auto alloc = [&](size_t bytes) -> void* {
        void* p = base + off;
        off += (bytes + 255) & ~(size_t)255;
        return p;
    };
    // zero-init region: [deg | gcur | ovcnt] — one memset
    int* zbase    = (int*)alloc((size_t)(N_NODES + NBUK + 64) * 4);
    int* deg      = zbase;
    int* gcur     = zbase + N_NODES;
    int* ovcnt    = zbase + N_NODES + NBUK;
    int* row_ptr  = (int*)alloc((size_t)(N_NODES + 1) * 4);
    int* cursor   = (int*)alloc((size_t)N_NODES * 4);
    float* dinv   = (float*)alloc((size_t)N_NODES * 4);
    int* bsum     = (int*)alloc((size_t)SCAN_NB * 4);
    unsigned* staging = (unsigned*)alloc((size_t)NBUK * SCAP * 4);   // 9.6 MB
    unsigned long long* ovbuf = (unsigned long long*)alloc((size_t)OV_CAP * 8);
    int* csr_src  = (int*)alloc((size_t)N_EDGES * 4);
    unsigned short* Wt1 = (unsigned short*)alloc((size_t)F_HID * F_IN * 2);
    unsigned short* Wt2 = (unsigned short*)alloc((size_t)F_OUT * F_HID * 2);
    unsigned short* g1  = (unsigned short*)alloc((size_t)N_NODES * F_HID * 2);
    unsigned short* h1  = (unsigned short*)alloc((size_t)N_NODES * F_HID * 2);
    unsigned short* g2  = g1;  // g1 dead after agg1

    hipMemsetAsync(zbase, 0, (size_t)(N_NODES + NBUK + 64) * 4, stream);
    partition_kernel<<<NBLK_A, 256, 0, stream>>>(src, dst, deg, staging, gcur, ovbuf, ovcnt);
    block_sum_kernel<<<SCAN_NB, 256, 0, stream>>>(deg, bsum, N_NODES);
    scan_partials_kernel<<<1, 512, 0, stream>>>(bsum, SCAN_NB);
    scan_final_kernel<<<SCAN_NB, 256, 0, stream>>>(deg, bsum, row_ptr, cursor, dinv, N_NODES);
    fill_kernel<<<NBUK, 256, 0, stream>>>(staging, gcur, cursor, csr_src, ovbuf, ovcnt);
    transpose_w_kernel<<<(F_HID * F_IN + F_OUT * F_HID + 255) / 256, 256, 0, stream>>>(
        W1, W2, Wt1, Wt2);

    int gblocks = (N_NODES + 127) / 128;  // 782
    gemm_direct_kernel<F_HID, F_IN, false><<<gblocks, 256, 0, stream>>>(
        (const void*)x, Wt1, dinv, g1, N_NODES);
    agg1_kernel<<<(N_NODES + 3) / 4, 256, 0, stream>>>(
        (const unsigned int*)g1, row_ptr, csr_src, dinv, b1, (unsigned int*)h1);

    gemm_direct_kernel<F_OUT, F_HID, true><<<gblocks, 256, 0, stream>>>(
        (const void*)h1, Wt2, dinv, g2, N_NODES);
    agg2_lsm_kernel<<<(N_NODES + 3) / 4, 256, 0, stream>>>(
        g2, row_ptr, csr_src, dinv, b2, out);
}